// Round 2
// baseline (3366.890 us; speedup 1.0000x reference)
//
#include <hip/hip_runtime.h>
#include <math.h>

#define HFEAT 75
#define WFEAT 120
#define NPIX (HFEAT*WFEAT)      // 9000
#define NANCH 81000
#define SORTN 131072
#define PRE 6000
#define POST 300
#define SUPW 94                 // ceil(6000/64)

// 9 base anchors (base_size=16, ratios .5/1/2, scales 8/16/32), precomputed
// exactly per the numpy reference (incl. banker's rounding of 11.5 -> 12).
__constant__ float ANCH[9][4] = {
  {-84.f,-40.f,99.f,55.f},  {-176.f,-88.f,191.f,103.f},{-360.f,-184.f,375.f,199.f},
  {-56.f,-56.f,71.f,71.f},  {-120.f,-120.f,135.f,135.f},{-248.f,-248.f,263.f,263.f},
  {-36.f,-80.f,51.f,95.f},  {-80.f,-168.f,95.f,183.f}, {-168.f,-344.f,183.f,359.f}};

// ---------------- conv 3x3 + bias + relu ----------------
// tile: 64 oc x 1 row x 64 cols, 256 threads, each 4x4 outputs.
// chunked fp32 accumulation (8-ic partials) for lower rounding error.
__global__ __launch_bounds__(256) void conv3_relu(
    const float* __restrict__ in, const float* __restrict__ w,
    const float* __restrict__ bias, float* __restrict__ out)
{
  __shared__ float in_s[8][3][68];
  __shared__ float w_s[72][66];
  const int tid = threadIdx.x;
  const int obase = blockIdx.x * 64;
  const int y = blockIdx.y;
  const int x0 = blockIdx.z * 64;
  const int tx = tid & 15, ty = tid >> 4;
  const int oc4 = tx * 4, px4 = ty * 4;
  float tot[4][4];
  #pragma unroll
  for (int p = 0; p < 4; ++p)
    #pragma unroll
    for (int o = 0; o < 4; ++o) tot[p][o] = 0.f;

  for (int ic0 = 0; ic0 < 512; ic0 += 8) {
    __syncthreads();
    for (int i = tid; i < 8*3*66; i += 256) {
      int ic = i / 198, r = i % 198;
      int dy = r / 66, xx = r % 66;
      int gy = y + dy - 1, gx = x0 + xx - 1;
      float v = 0.f;
      if ((unsigned)gy < 75u && (unsigned)gx < 120u)
        v = in[(ic0 + ic) * NPIX + gy * WFEAT + gx];
      in_s[ic][dy][xx] = v;
    }
    for (int i = tid; i < 64*72; i += 256) {
      int oc = i / 72, t = i % 72;
      w_s[t][oc] = w[(obase + oc) * 4608 + ic0 * 9 + t];
    }
    __syncthreads();
    float acc[4][4];
    #pragma unroll
    for (int p = 0; p < 4; ++p)
      #pragma unroll
      for (int o = 0; o < 4; ++o) acc[p][o] = 0.f;
    #pragma unroll
    for (int ic = 0; ic < 8; ++ic) {
      #pragma unroll
      for (int dy = 0; dy < 3; ++dy) {
        float iv[6];
        #pragma unroll
        for (int j = 0; j < 6; ++j) iv[j] = in_s[ic][dy][px4 + j];
        #pragma unroll
        for (int dx = 0; dx < 3; ++dx) {
          const int t = ic * 9 + dy * 3 + dx;
          float w0 = w_s[t][oc4 + 0], w1 = w_s[t][oc4 + 1];
          float w2 = w_s[t][oc4 + 2], w3 = w_s[t][oc4 + 3];
          #pragma unroll
          for (int p = 0; p < 4; ++p) {
            float xv = iv[p + dx];
            acc[p][0] += xv * w0; acc[p][1] += xv * w1;
            acc[p][2] += xv * w2; acc[p][3] += xv * w3;
          }
        }
      }
    }
    #pragma unroll
    for (int p = 0; p < 4; ++p)
      #pragma unroll
      for (int o = 0; o < 4; ++o) tot[p][o] += acc[p][o];
  }
  #pragma unroll
  for (int o = 0; o < 4; ++o) {
    float bv = bias[obase + oc4 + o];
    #pragma unroll
    for (int p = 0; p < 4; ++p) {
      int x = x0 + px4 + p;
      if (x < WFEAT) {
        float v = tot[p][o] + bv;
        out[(obase + oc4 + o) * NPIX + y * WFEAT + x] = v > 0.f ? v : 0.f;
      }
    }
  }
}

// ---------------- 1x1 convs: 18 cls + 36 bbox channels ----------------
__global__ __launch_bounds__(256) void conv1x1(
    const float* __restrict__ rpn,
    const float* __restrict__ wc, const float* __restrict__ bc,
    const float* __restrict__ wb, const float* __restrict__ bb,
    float* __restrict__ cls, float* __restrict__ bbox)
{
  __shared__ float r_s[64][128];
  __shared__ float w_s[54][64];
  const int tid = threadIdx.x;
  const int px0 = blockIdx.x * 128;
  const int px = tid & 127, g = tid >> 7;
  float tot[27];
  #pragma unroll
  for (int j = 0; j < 27; ++j) tot[j] = 0.f;
  for (int ic0 = 0; ic0 < 512; ic0 += 64) {
    __syncthreads();
    for (int i = tid; i < 64*128; i += 256) {
      int ic = i >> 7, p = i & 127;
      int gp = px0 + p;
      r_s[ic][p] = (gp < NPIX) ? rpn[(ic0 + ic) * NPIX + gp] : 0.f;
    }
    for (int i = tid; i < 54*64; i += 256) {
      int c = i >> 6, ic = i & 63;
      w_s[c][ic] = (c < 18) ? wc[c * 512 + ic0 + ic] : wb[(c - 18) * 512 + ic0 + ic];
    }
    __syncthreads();
    float acc[27];
    #pragma unroll
    for (int j = 0; j < 27; ++j) acc[j] = 0.f;
    for (int ic = 0; ic < 64; ++ic) {
      float iv = r_s[ic][px];
      #pragma unroll
      for (int j = 0; j < 27; ++j) acc[j] += iv * w_s[g * 27 + j][ic];
    }
    #pragma unroll
    for (int j = 0; j < 27; ++j) tot[j] += acc[j];
  }
  int gp = px0 + px;
  if (gp < NPIX) {
    for (int j = 0; j < 27; ++j) {
      int c = g * 27 + j;
      if (c < 18) cls[c * NPIX + gp] = tot[j] + bc[c];
      else        bbox[(c - 18) * NPIX + gp] = tot[j] + bb[c - 18];
    }
  }
}

// ---------------- score keys + box decode ----------------
__device__ inline unsigned long long dkey(double d) {
  long long b = __double_as_longlong(d);
  unsigned long long u = (unsigned long long)b;
  return (b < 0) ? ~u : (u | 0x8000000000000000ull);
}

__global__ void decode_score(
    const float* __restrict__ cls, const float* __restrict__ bbox,
    float* __restrict__ props, unsigned long long* __restrict__ keys)
{
  int i = blockIdx.x * 256 + threadIdx.x;
  if (i >= SORTN) return;
  if (i >= NANCH) { keys[i] = 0ull; return; }
  int a = i % 9, p = i / 9;
  int x = p % WFEAT, y = p / WFEAT;
  // fg = sigmoid(c1-c0); monotonic in d = c1-c0, so sort by d.
  float c0 = cls[a * NPIX + p], c1 = cls[(9 + a) * NPIX + p];
  double d = (double)c1 - (double)c0;
  unsigned long long s = dkey(d);
  // low 17 bits: descending-value, ascending-index total order (jax top_k).
  keys[i] = (s & ~0x1FFFFull) | (unsigned long long)(0x1FFFFu - (unsigned)i);

  double ax1 = (double)ANCH[a][0] + 16.0 * x;
  double ay1 = (double)ANCH[a][1] + 16.0 * y;
  double ax2 = (double)ANCH[a][2] + 16.0 * x;
  double ay2 = (double)ANCH[a][3] + 16.0 * y;
  double aw = ax2 - ax1 + 1.0, ah = ay2 - ay1 + 1.0;
  double cx = ax1 + 0.5 * aw,  cy = ay1 + 0.5 * ah;
  double d0 = (double)bbox[(4*a+0) * NPIX + p];
  double d1 = (double)bbox[(4*a+1) * NPIX + p];
  double d2 = (double)bbox[(4*a+2) * NPIX + p];
  double d3 = (double)bbox[(4*a+3) * NPIX + p];
  double pcx = d0 * aw + cx, pcy = d1 * ah + cy;
  double pw = exp(d2) * aw,  ph = exp(d3) * ah;
  double bx1 = pcx - 0.5 * pw, by1 = pcy - 0.5 * ph;
  double bx2 = pcx + 0.5 * pw, by2 = pcy + 0.5 * ph;
  bx1 = fmin(fmax(bx1, 0.0), 1919.0); by1 = fmin(fmax(by1, 0.0), 1199.0);
  bx2 = fmin(fmax(bx2, 0.0), 1919.0); by2 = fmin(fmax(by2, 0.0), 1199.0);
  props[i*4+0] = (float)bx1; props[i*4+1] = (float)by1;
  props[i*4+2] = (float)bx2; props[i*4+3] = (float)by2;
}

// ---------------- hybrid bitonic sort (descending), N = 131072 ----------------
__device__ inline void cswap(unsigned long long* s, int lo, int hi, bool dirDesc) {
  unsigned long long a = s[lo], b = s[hi];
  bool sw = dirDesc ? (a < b) : (a > b);
  if (sw) { s[lo] = b; s[hi] = a; }
}

__global__ __launch_bounds__(1024) void bsort_local(unsigned long long* __restrict__ keys)
{
  __shared__ unsigned long long s[2048];
  const int base = blockIdx.x * 2048;
  const int tid = threadIdx.x;
  s[tid] = keys[base + tid];
  s[tid + 1024] = keys[base + tid + 1024];
  __syncthreads();
  for (int k = 2; k <= 2048; k <<= 1) {
    for (int j = k >> 1; j >= 1; j >>= 1) {
      int lo = ((tid & ~(j - 1)) << 1) | (tid & (j - 1));
      bool dirDesc = (((base + lo) & k) == 0);
      cswap(s, lo, lo + j, dirDesc);
      __syncthreads();
    }
  }
  keys[base + tid] = s[tid];
  keys[base + tid + 1024] = s[tid + 1024];
}

__global__ void bsort_gpass(unsigned long long* __restrict__ keys, int k, int j)
{
  int t = blockIdx.x * 256 + threadIdx.x;      // 65536 pairs
  int lo = ((t & ~(j - 1)) << 1) | (t & (j - 1));
  int hi = lo + j;
  bool dirDesc = ((lo & k) == 0);
  unsigned long long a = keys[lo], b = keys[hi];
  bool sw = dirDesc ? (a < b) : (a > b);
  if (sw) { keys[lo] = b; keys[hi] = a; }
}

__global__ __launch_bounds__(1024) void bsort_lmerge(unsigned long long* __restrict__ keys, int k)
{
  __shared__ unsigned long long s[2048];
  const int base = blockIdx.x * 2048;
  const int tid = threadIdx.x;
  s[tid] = keys[base + tid];
  s[tid + 1024] = keys[base + tid + 1024];
  __syncthreads();
  for (int j = 1024; j >= 1; j >>= 1) {
    int lo = ((tid & ~(j - 1)) << 1) | (tid & (j - 1));
    bool dirDesc = (((base + lo) & k) == 0);
    cswap(s, lo, lo + j, dirDesc);
    __syncthreads();
  }
  keys[base + tid] = s[tid];
  keys[base + tid + 1024] = s[tid + 1024];
}

__global__ void gather_topk(const unsigned long long* __restrict__ keys,
                            const float* __restrict__ props, float* __restrict__ boxes)
{
  int i = blockIdx.x * 256 + threadIdx.x;
  if (i >= PRE) return;
  unsigned idx = 0x1FFFFu - (unsigned)(keys[i] & 0x1FFFFull);
  ((float4*)boxes)[i] = ((const float4*)props)[idx];
}

// ---------------- NMS: suppression bit-matrix then serial scan ----------------
__global__ __launch_bounds__(64) void nms_sup(const float* __restrict__ boxes,
                                              unsigned long long* __restrict__ sup)
{
  const int bi = blockIdx.x, bj = blockIdx.y;
  const int j0 = bj * 64;
  __shared__ float4 cb[64];
  int jt = j0 + threadIdx.x;
  cb[threadIdx.x] = (jt < PRE) ? ((const float4*)boxes)[jt] : make_float4(0,0,0,0);
  __syncthreads();
  int i = bi * 64 + threadIdx.x;
  if (i >= PRE) return;
  float4 b = ((const float4*)boxes)[i];
  double x1 = b.x, y1 = b.y, x2 = b.z, y2 = b.w;
  double area_i = (x2 - x1 + 1.0) * (y2 - y1 + 1.0);
  unsigned long long m = 0ull;
  for (int jj = 0; jj < 64; ++jj) {
    int j = j0 + jj;
    if (j > i && j < PRE) {
      float4 c = cb[jj];
      double xx1 = fmax(x1, (double)c.x), yy1 = fmax(y1, (double)c.y);
      double xx2 = fmin(x2, (double)c.z), yy2 = fmin(y2, (double)c.w);
      double iw = xx2 - xx1 + 1.0, ih = yy2 - yy1 + 1.0;
      if (iw > 0.0 && ih > 0.0) {
        double inter = iw * ih;
        double area_j = ((double)c.z - c.x + 1.0) * ((double)c.w - c.y + 1.0);
        double iou = inter / (area_i + area_j - inter);
        if (iou > 0.7) m |= (1ull << jj);
      }
    }
  }
  sup[(long)i * SUPW + bj] = m;
}

// single wave: sequential greedy scan matching the reference fori_loop, then
// top-300 selection (kept in order, then suppressed in order = jax -inf ties).
__global__ __launch_bounds__(64) void nms_scan(const unsigned long long* __restrict__ sup,
                                               const float* __restrict__ boxes,
                                               float* __restrict__ rois)
{
  volatile __shared__ unsigned long long keep[SUPW];
  __shared__ int pos[POST];
  const int tid = threadIdx.x;
  for (int wdx = tid; wdx < SUPW; wdx += 64) keep[wdx] = ~0ull;
  __syncthreads();
  for (int i = 0; i < PRE; ++i) {
    bool kept = (keep[i >> 6] >> (i & 63)) & 1ull;
    if (kept) {
      for (int wdx = tid; wdx < SUPW; wdx += 64)
        keep[wdx] &= ~sup[(long)i * SUPW + wdx];
    }
  }
  __syncthreads();
  if (tid == 0) {
    int cnt = 0;
    for (int i = 0; i < PRE && cnt < POST; ++i)
      if ((keep[i >> 6] >> (i & 63)) & 1ull) pos[cnt++] = i;
    for (int i = 0; i < PRE && cnt < POST; ++i)
      if (!((keep[i >> 6] >> (i & 63)) & 1ull)) pos[cnt++] = i;
  }
  __syncthreads();
  for (int t = tid; t < POST * 4; t += 64)
    rois[t] = boxes[pos[t >> 2] * 4 + (t & 3)];
}

// ---------------- crop_and_resize (14x14 bilinear) + 2x2 maxpool ----------------
__global__ __launch_bounds__(256) void crop_pool(
    const float* __restrict__ feat, const float* __restrict__ rois,
    float* __restrict__ out)
{
  __shared__ int xl[14], xh[14], yl[14], yh[14];
  __shared__ float wx[14], wy[14];
  const int n = blockIdx.x;
  const int tid = threadIdx.x;
  if (tid < 14) {
    float4 r = ((const float4*)rois)[n];
    double fx1 = (double)r.x / 16.0, fy1 = (double)r.y / 16.0;
    double fx2 = (double)r.z / 16.0, fy2 = (double)r.w / 16.0;
    double x1n = fx1 / 119.0, x2n = fx2 / 119.0;
    double y1n = fy1 / 74.0,  y2n = fy2 / 74.0;
    double t = (double)tid / 13.0;
    double xs = (x1n + t * (x2n - x1n)) * 119.0;
    double ys = (y1n + t * (y2n - y1n)) * 74.0;
    double xf = floor(xs), yf = floor(ys);
    wx[tid] = (float)(xs - xf);
    wy[tid] = (float)(ys - yf);
    int xli = (int)fmin(fmax(xf, 0.0), 119.0);
    int yli = (int)fmin(fmax(yf, 0.0), 74.0);
    xl[tid] = xli; xh[tid] = (xli + 1 > 119) ? 119 : xli + 1;
    yl[tid] = yli; yh[tid] = (yli + 1 > 74) ? 74 : yli + 1;
  }
  __syncthreads();
  for (int t = tid; t < 512 * 49; t += 256) {
    int c = t / 49, r = t % 49;
    int py = r / 7, px = r % 7;
    const float* fc = feat + c * NPIX;
    float m = -1e30f;
    #pragma unroll
    for (int sy = 0; sy < 2; ++sy) {
      int iy = py * 2 + sy;
      float wyv = wy[iy];
      int ylo = yl[iy] * WFEAT, yhi = yh[iy] * WFEAT;
      #pragma unroll
      for (int sx = 0; sx < 2; ++sx) {
        int ix = px * 2 + sx;
        float wxv = wx[ix];
        float v00 = fc[ylo + xl[ix]], v01 = fc[ylo + xh[ix]];
        float v10 = fc[yhi + xl[ix]], v11 = fc[yhi + xh[ix]];
        float top = v00 * (1.f - wxv) + v01 * wxv;
        float bot = v10 * (1.f - wxv) + v11 * wxv;
        float val = top * (1.f - wyv) + bot * wyv;
        m = fmaxf(m, val);
      }
    }
    out[(n * 512 + c) * 49 + r] = m;
  }
}

extern "C" void kernel_launch(void* const* d_in, const int* in_sizes, int n_in,
                              void* d_out, int out_size, void* d_ws, size_t ws_size,
                              hipStream_t stream) {
  const float* net    = (const float*)d_in[0];
  const float* rpn_w  = (const float*)d_in[1];
  const float* rpn_b  = (const float*)d_in[2];
  const float* cls_w  = (const float*)d_in[3];
  const float* cls_b  = (const float*)d_in[4];
  const float* bbox_w = (const float*)d_in[5];
  const float* bbox_b = (const float*)d_in[6];
  float* out = (float*)d_out;

  // rpn activations (18.43 MB) live in d_out scratch (30.1 MB), dead before
  // the final crop_pool write. d_ws holds only ~8.9 MB.
  float* rpn = out;
  float* cls   = (float*)d_ws;                    // 162,000 f
  float* bbox  = cls + 162000;                    // 324,000 f
  float* props = bbox + 324000;                   // 324,000 f
  unsigned long long* keys = (unsigned long long*)(props + 324000);  // 131072 u64
  float* boxes_k = (float*)(keys + SORTN);        // 24,000 f
  unsigned long long* sup = (unsigned long long*)(boxes_k + PRE * 4); // 6000*94 u64
  float* rois = (float*)(sup + (size_t)PRE * SUPW); // 1,200 f

  dim3 gconv(8, 75, 2);
  conv3_relu<<<gconv, 256, 0, stream>>>(net, rpn_w, rpn_b, rpn);
  conv1x1<<<71, 256, 0, stream>>>(rpn, cls_w, cls_b, bbox_w, bbox_b, cls, bbox);
  decode_score<<<SORTN / 256, 256, 0, stream>>>(cls, bbox, props, keys);

  bsort_local<<<SORTN / 2048, 1024, 0, stream>>>(keys);
  for (int k = 4096; k <= SORTN; k <<= 1) {
    for (int j = k >> 1; j >= 2048; j >>= 1)
      bsort_gpass<<<SORTN / 512, 256, 0, stream>>>(keys, k, j);
    bsort_lmerge<<<SORTN / 2048, 1024, 0, stream>>>(keys, k);
  }
  gather_topk<<<(PRE + 255) / 256, 256, 0, stream>>>(keys, props, boxes_k);

  dim3 gsup(SUPW, SUPW);
  nms_sup<<<gsup, 64, 0, stream>>>(boxes_k, sup);
  nms_scan<<<1, 64, 0, stream>>>(sup, boxes_k, rois);
  crop_pool<<<POST, 256, 0, stream>>>(net, rois, out);
}

// Round 5
// 2164.668 us; speedup vs baseline: 1.5554x; 1.5554x over previous
//
#include <hip/hip_runtime.h>
#include <math.h>

#define HFEAT 75
#define WFEAT 120
#define NPIX (HFEAT*WFEAT)      // 9000
#define NANCH 81000
#define PRE 6000
#define POST 300
#define SUPW 94                 // ceil(6000/64)
#define HBITS 18
#define HBUCK (1<<HBITS)        // 262144
#define HCHUNK (HBUCK/1024)     // 256

// 9 base anchors (base_size=16, ratios .5/1/2, scales 8/16/32), precomputed
// exactly per the numpy reference (incl. banker's rounding of 11.5 -> 12).
__constant__ float ANCH[9][4] = {
  {-84.f,-40.f,99.f,55.f},  {-176.f,-88.f,191.f,103.f},{-360.f,-184.f,375.f,199.f},
  {-56.f,-56.f,71.f,71.f},  {-120.f,-120.f,135.f,135.f},{-248.f,-248.f,263.f,263.f},
  {-36.f,-80.f,51.f,95.f},  {-80.f,-168.f,95.f,183.f}, {-168.f,-344.f,183.f,359.f}};

// ---------------- conv 3x3 + bias + relu ----------------
__global__ __launch_bounds__(256) void conv3_relu(
    const float* __restrict__ in, const float* __restrict__ w,
    const float* __restrict__ bias, float* __restrict__ out)
{
  __shared__ float in_s[8][3][68];
  __shared__ float w_s[72][66];
  const int tid = threadIdx.x;
  const int obase = blockIdx.x * 64;
  const int y = blockIdx.y;
  const int x0 = blockIdx.z * 64;
  const int tx = tid & 15, ty = tid >> 4;
  const int oc4 = tx * 4, px4 = ty * 4;
  float tot[4][4];
  #pragma unroll
  for (int p = 0; p < 4; ++p)
    #pragma unroll
    for (int o = 0; o < 4; ++o) tot[p][o] = 0.f;

  for (int ic0 = 0; ic0 < 512; ic0 += 8) {
    __syncthreads();
    for (int i = tid; i < 8*3*66; i += 256) {
      int ic = i / 198, r = i % 198;
      int dy = r / 66, xx = r % 66;
      int gy = y + dy - 1, gx = x0 + xx - 1;
      float v = 0.f;
      if ((unsigned)gy < 75u && (unsigned)gx < 120u)
        v = in[(ic0 + ic) * NPIX + gy * WFEAT + gx];
      in_s[ic][dy][xx] = v;
    }
    for (int i = tid; i < 64*72; i += 256) {
      int oc = i / 72, t = i % 72;
      w_s[t][oc] = w[(obase + oc) * 4608 + ic0 * 9 + t];
    }
    __syncthreads();
    float acc[4][4];
    #pragma unroll
    for (int p = 0; p < 4; ++p)
      #pragma unroll
      for (int o = 0; o < 4; ++o) acc[p][o] = 0.f;
    #pragma unroll
    for (int ic = 0; ic < 8; ++ic) {
      #pragma unroll
      for (int dy = 0; dy < 3; ++dy) {
        float iv[6];
        #pragma unroll
        for (int j = 0; j < 6; ++j) iv[j] = in_s[ic][dy][px4 + j];
        #pragma unroll
        for (int dx = 0; dx < 3; ++dx) {
          const int t = ic * 9 + dy * 3 + dx;
          float w0 = w_s[t][oc4 + 0], w1 = w_s[t][oc4 + 1];
          float w2 = w_s[t][oc4 + 2], w3 = w_s[t][oc4 + 3];
          #pragma unroll
          for (int p = 0; p < 4; ++p) {
            float xv = iv[p + dx];
            acc[p][0] += xv * w0; acc[p][1] += xv * w1;
            acc[p][2] += xv * w2; acc[p][3] += xv * w3;
          }
        }
      }
    }
    #pragma unroll
    for (int p = 0; p < 4; ++p)
      #pragma unroll
      for (int o = 0; o < 4; ++o) tot[p][o] += acc[p][o];
  }
  #pragma unroll
  for (int o = 0; o < 4; ++o) {
    float bv = bias[obase + oc4 + o];
    #pragma unroll
    for (int p = 0; p < 4; ++p) {
      int x = x0 + px4 + p;
      if (x < WFEAT) {
        float v = tot[p][o] + bv;
        out[(obase + oc4 + o) * NPIX + y * WFEAT + x] = v > 0.f ? v : 0.f;
      }
    }
  }
}

// ---------------- 1x1 convs: 18 cls + 36 bbox channels ----------------
__global__ __launch_bounds__(256) void conv1x1(
    const float* __restrict__ rpn,
    const float* __restrict__ wc, const float* __restrict__ bc,
    const float* __restrict__ wb, const float* __restrict__ bb,
    float* __restrict__ cls, float* __restrict__ bbox)
{
  __shared__ float r_s[64][128];
  __shared__ float w_s[54][64];
  const int tid = threadIdx.x;
  const int px0 = blockIdx.x * 128;
  const int px = tid & 127, g = tid >> 7;
  float tot[27];
  #pragma unroll
  for (int j = 0; j < 27; ++j) tot[j] = 0.f;
  for (int ic0 = 0; ic0 < 512; ic0 += 64) {
    __syncthreads();
    for (int i = tid; i < 64*128; i += 256) {
      int ic = i >> 7, p = i & 127;
      int gp = px0 + p;
      r_s[ic][p] = (gp < NPIX) ? rpn[(ic0 + ic) * NPIX + gp] : 0.f;
    }
    for (int i = tid; i < 54*64; i += 256) {
      int c = i >> 6, ic = i & 63;
      w_s[c][ic] = (c < 18) ? wc[c * 512 + ic0 + ic] : wb[(c - 18) * 512 + ic0 + ic];
    }
    __syncthreads();
    float acc[27];
    #pragma unroll
    for (int j = 0; j < 27; ++j) acc[j] = 0.f;
    for (int ic = 0; ic < 64; ++ic) {
      float iv = r_s[ic][px];
      #pragma unroll
      for (int j = 0; j < 27; ++j) acc[j] += iv * w_s[g * 27 + j][ic];
    }
    #pragma unroll
    for (int j = 0; j < 27; ++j) tot[j] += acc[j];
  }
  int gp = px0 + px;
  if (gp < NPIX) {
    for (int j = 0; j < 27; ++j) {
      int c = g * 27 + j;
      if (c < 18) cls[c * NPIX + gp] = tot[j] + bc[c];
      else        bbox[(c - 18) * NPIX + gp] = tot[j] + bb[c - 18];
    }
  }
}

// ---------------- score keys + box decode ----------------
__device__ inline unsigned long long dkey(double d) {
  long long b = __double_as_longlong(d);
  unsigned long long u = (unsigned long long)b;
  return (b < 0) ? ~u : (u | 0x8000000000000000ull);
}

__global__ void decode_score(
    const float* __restrict__ cls, const float* __restrict__ bbox,
    float* __restrict__ props, unsigned long long* __restrict__ keys)
{
  int i = blockIdx.x * 256 + threadIdx.x;
  if (i >= NANCH) return;
  int a = i % 9, p = i / 9;
  int x = p % WFEAT, y = p / WFEAT;
  // fg = sigmoid(c1-c0); monotonic in d = c1-c0, so order by d.
  float c0 = cls[a * NPIX + p], c1 = cls[(9 + a) * NPIX + p];
  double d = (double)c1 - (double)c0;
  unsigned long long s = dkey(d);
  // low 17 bits: descending-value, ascending-index total order (jax top_k).
  keys[i] = (s & ~0x1FFFFull) | (unsigned long long)(0x1FFFFu - (unsigned)i);

  double ax1 = (double)ANCH[a][0] + 16.0 * x;
  double ay1 = (double)ANCH[a][1] + 16.0 * y;
  double ax2 = (double)ANCH[a][2] + 16.0 * x;
  double ay2 = (double)ANCH[a][3] + 16.0 * y;
  double aw = ax2 - ax1 + 1.0, ah = ay2 - ay1 + 1.0;
  double cx = ax1 + 0.5 * aw,  cy = ay1 + 0.5 * ah;
  double d0 = (double)bbox[(4*a+0) * NPIX + p];
  double d1 = (double)bbox[(4*a+1) * NPIX + p];
  double d2 = (double)bbox[(4*a+2) * NPIX + p];
  double d3 = (double)bbox[(4*a+3) * NPIX + p];
  double pcx = d0 * aw + cx, pcy = d1 * ah + cy;
  double pw = exp(d2) * aw,  ph = exp(d3) * ah;
  double bx1 = pcx - 0.5 * pw, by1 = pcy - 0.5 * ph;
  double bx2 = pcx + 0.5 * pw, by2 = pcy + 0.5 * ph;
  bx1 = fmin(fmax(bx1, 0.0), 1919.0); by1 = fmin(fmax(by1, 0.0), 1199.0);
  bx2 = fmin(fmax(bx2, 0.0), 1919.0); by2 = fmin(fmax(by2, 0.0), 1199.0);
  props[i*4+0] = (float)bx1; props[i*4+1] = (float)by1;
  props[i*4+2] = (float)bx2; props[i*4+3] = (float)by2;
}

// ---------------- exact top-6000 select (replaces full bitonic sort) --------
// keys are unique u64 with a total order; find T = 6000th-largest exactly.
__global__ void hist_hi(const unsigned long long* __restrict__ keys,
                        unsigned* __restrict__ hist)
{
  int i = blockIdx.x * 256 + threadIdx.x;
  if (i < NANCH) atomicAdd(&hist[(unsigned)(keys[i] >> 46)], 1u);
}

__global__ __launch_bounds__(1024) void select_thresh(
    const unsigned long long* __restrict__ keys,
    const unsigned* __restrict__ hist, unsigned long long* __restrict__ thresh)
{
  __shared__ unsigned csum[1024];
  __shared__ int sh_bucket, sh_rank, sh_cnt;
  __shared__ unsigned long long buf[4096];
  const int tid = threadIdx.x;
  unsigned s = 0;
  for (int i = 0; i < HCHUNK; ++i) s += hist[tid * HCHUNK + i];
  csum[tid] = s;
  __syncthreads();
  if (tid == 0) {
    unsigned cum = 0; int tc = 0;
    for (int t = 1023; t >= 0; --t) {
      if (cum + csum[t] >= PRE) { tc = t; break; }
      cum += csum[t];
    }
    int B = tc * HCHUNK;
    for (int b0 = HCHUNK - 1; b0 >= 0; --b0) {
      unsigned h = hist[tc * HCHUNK + b0];
      if (cum + h >= PRE) { B = tc * HCHUNK + b0; break; }
      cum += h;
    }
    sh_bucket = B;
    sh_rank = PRE - (int)cum;   // 1-indexed rank of T within bucket B
    sh_cnt = 0;
  }
  __syncthreads();
  const int B = sh_bucket, r = sh_rank;
  for (int i = tid; i < NANCH; i += 1024) {
    unsigned long long kv = keys[i];
    if ((int)(kv >> 46) == B) {
      int p = atomicAdd(&sh_cnt, 1);
      if (p < 4096) buf[p] = kv;
    }
  }
  __syncthreads();
  int c = sh_cnt < 4096 ? sh_cnt : 4096;
  for (int i = tid; i < c; i += 1024) {
    unsigned long long kv = buf[i];
    int gt = 0;
    for (int j = 0; j < c; ++j) gt += (buf[j] > kv) ? 1 : 0;
    if (gt == r - 1) *thresh = kv;     // unique ranks: exactly one writer
  }
}

__global__ void compact_ge(const unsigned long long* __restrict__ keys,
                           const unsigned long long* __restrict__ thresh,
                           unsigned long long* __restrict__ keys2,
                           unsigned* __restrict__ counter)
{
  int i = blockIdx.x * 256 + threadIdx.x;
  if (i >= NANCH) return;
  unsigned long long kv = keys[i];
  if (kv >= *thresh) keys2[atomicAdd(counter, 1u)] = kv;   // exactly 6000
}

// single-block bitonic sort of 8192 (6000 real + 0-padding), descending
__global__ __launch_bounds__(1024) void sort8192(unsigned long long* __restrict__ keys2)
{
  extern __shared__ unsigned long long s[];
  const int tid = threadIdx.x;
  for (int e = tid; e < 8192; e += 1024) s[e] = (e < PRE) ? keys2[e] : 0ull;
  __syncthreads();
  for (int k = 2; k <= 8192; k <<= 1) {
    for (int j = k >> 1; j >= 1; j >>= 1) {
      for (int e = tid; e < 4096; e += 1024) {
        int lo = ((e & ~(j - 1)) << 1) | (e & (j - 1));
        int hi = lo + j;
        bool dirDesc = ((lo & k) == 0);
        unsigned long long a = s[lo], b = s[hi];
        if (dirDesc ? (a < b) : (a > b)) { s[lo] = b; s[hi] = a; }
      }
      __syncthreads();
    }
  }
  for (int e = tid; e < PRE; e += 1024) keys2[e] = s[e];
}

__global__ void gather_topk(const unsigned long long* __restrict__ keys2,
                            const float* __restrict__ props, float* __restrict__ boxes)
{
  int i = blockIdx.x * 256 + threadIdx.x;
  if (i >= PRE) return;
  unsigned idx = 0x1FFFFu - (unsigned)(keys2[i] & 0x1FFFFull);
  ((float4*)boxes)[i] = ((const float4*)props)[idx];
}

// ---------------- NMS: suppression bit-matrix then blocked scan ----------------
__global__ __launch_bounds__(64) void nms_sup(const float* __restrict__ boxes,
                                              unsigned long long* __restrict__ sup)
{
  const int bi = blockIdx.x, bj = blockIdx.y;
  const int j0 = bj * 64;
  __shared__ float4 cb[64];
  int jt = j0 + threadIdx.x;
  cb[threadIdx.x] = (jt < PRE) ? ((const float4*)boxes)[jt] : make_float4(0,0,0,0);
  __syncthreads();
  int i = bi * 64 + threadIdx.x;
  if (i >= PRE) return;
  float4 b = ((const float4*)boxes)[i];
  double x1 = b.x, y1 = b.y, x2 = b.z, y2 = b.w;
  double area_i = (x2 - x1 + 1.0) * (y2 - y1 + 1.0);
  unsigned long long m = 0ull;
  for (int jj = 0; jj < 64; ++jj) {
    int j = j0 + jj;
    if (j > i && j < PRE) {
      float4 c = cb[jj];
      double xx1 = fmax(x1, (double)c.x), yy1 = fmax(y1, (double)c.y);
      double xx2 = fmin(x2, (double)c.z), yy2 = fmin(y2, (double)c.w);
      double iw = xx2 - xx1 + 1.0, ih = yy2 - yy1 + 1.0;
      if (iw > 0.0 && ih > 0.0) {
        double inter = iw * ih;
        double area_j = ((double)c.z - c.x + 1.0) * ((double)c.w - c.y + 1.0);
        double iou = inter / (area_i + area_j - inter);
        if (iou > 0.7) m |= (1ull << jj);
      }
    }
  }
  sup[(long)i * SUPW + bj] = m;
}

// Blocked greedy scan, exactly equivalent to the reference fori_loop:
// per 64-block b: (1) serial in-register resolve of keep-word b (sup rows
// only hold j>i bits, so ascending k replicates the serial order), (2)
// 64-lane parallel masked-OR suppression of all trailing words.
__global__ __launch_bounds__(64) void nms_scan(const unsigned long long* __restrict__ sup,
                                               const float* __restrict__ boxes,
                                               float* __restrict__ rois)
{
  __shared__ unsigned long long keep[SUPW];
  __shared__ unsigned long long supl[64];
  __shared__ int kpre[SUPW], spre[SUPW];
  __shared__ int totK;
  __shared__ int pos[POST];
  const int tid = threadIdx.x;
  for (int w = tid; w < SUPW; w += 64) keep[w] = ~0ull;
  __syncthreads();

  for (int b = 0; b < SUPW; ++b) {
    int i = b * 64 + tid;
    supl[tid] = (i < PRE) ? sup[(long)i * SUPW + b] : 0ull;
    __syncthreads();
    unsigned long long kw = keep[b];
    #pragma unroll 8
    for (int k = 0; k < 64; ++k)
      kw &= ~(supl[k] & (0ull - ((kw >> k) & 1ull)));
    if (tid == 0) keep[b] = kw;
    const unsigned long long* colbase = sup + (long)(b * 64) * SUPW;
    for (int wdx = b + 1 + tid; wdx < SUPW; wdx += 64) {
      unsigned long long acc = 0ull;
      #pragma unroll 8
      for (int k = 0; k < 64; ++k)
        acc |= colbase[(long)k * SUPW + wdx] & (0ull - ((kw >> k) & 1ull));
      keep[wdx] &= ~acc;
    }
    __syncthreads();
  }

  // parallel top-300 selection: kept in index order, then suppressed
  // (jax top_k over {score, -inf} with index tie-break).
  if (tid == 0) {
    int kc = 0, sc = 0;
    for (int w = 0; w < SUPW; ++w) {
      unsigned long long valid = (w == SUPW - 1) ? ((1ull << 48) - 1ull) : ~0ull;
      kpre[w] = kc; spre[w] = sc;
      kc += __popcll(keep[w] & valid);
      sc += __popcll(~keep[w] & valid);
    }
    totK = kc;
  }
  __syncthreads();
  const int K = totK;
  for (int w = tid; w < SUPW; w += 64) {
    unsigned long long valid = (w == SUPW - 1) ? ((1ull << 48) - 1ull) : ~0ull;
    unsigned long long kk = keep[w] & valid;
    int r = kpre[w];
    while (kk && r < POST) {
      int k_ = __builtin_ctzll(kk); kk &= kk - 1ull;
      pos[r++] = w * 64 + k_;
    }
    unsigned long long ss = ~keep[w] & valid;
    int r2 = K + spre[w];
    while (ss && r2 < POST) {
      int k_ = __builtin_ctzll(ss); ss &= ss - 1ull;
      pos[r2++] = w * 64 + k_;
    }
  }
  __syncthreads();
  for (int t = tid; t < POST * 4; t += 64)
    rois[t] = boxes[pos[t >> 2] * 4 + (t & 3)];
}

// ---------------- crop_and_resize (14x14 bilinear) + 2x2 maxpool ----------------
__global__ __launch_bounds__(256) void crop_pool(
    const float* __restrict__ feat, const float* __restrict__ rois,
    float* __restrict__ out)
{
  __shared__ int xl[14], xh[14], yl[14], yh[14];
  __shared__ float wx[14], wy[14];
  const int n = blockIdx.x;
  const int tid = threadIdx.x;
  if (tid < 14) {
    float4 r = ((const float4*)rois)[n];
    double fx1 = (double)r.x / 16.0, fy1 = (double)r.y / 16.0;
    double fx2 = (double)r.z / 16.0, fy2 = (double)r.w / 16.0;
    double x1n = fx1 / 119.0, x2n = fx2 / 119.0;
    double y1n = fy1 / 74.0,  y2n = fy2 / 74.0;
    double t = (double)tid / 13.0;
    double xs = (x1n + t * (x2n - x1n)) * 119.0;
    double ys = (y1n + t * (y2n - y1n)) * 74.0;
    double xf = floor(xs), yf = floor(ys);
    wx[tid] = (float)(xs - xf);
    wy[tid] = (float)(ys - yf);
    int xli = (int)fmin(fmax(xf, 0.0), 119.0);
    int yli = (int)fmin(fmax(yf, 0.0), 74.0);
    xl[tid] = xli; xh[tid] = (xli + 1 > 119) ? 119 : xli + 1;
    yl[tid] = yli; yh[tid] = (yli + 1 > 74) ? 74 : yli + 1;
  }
  __syncthreads();
  for (int t = tid; t < 512 * 49; t += 256) {
    int c = t / 49, r = t % 49;
    int py = r / 7, px = r % 7;
    const float* fc = feat + c * NPIX;
    float m = -1e30f;
    #pragma unroll
    for (int sy = 0; sy < 2; ++sy) {
      int iy = py * 2 + sy;
      float wyv = wy[iy];
      int ylo = yl[iy] * WFEAT, yhi = yh[iy] * WFEAT;
      #pragma unroll
      for (int sx = 0; sx < 2; ++sx) {
        int ix = px * 2 + sx;
        float wxv = wx[ix];
        float v00 = fc[ylo + xl[ix]], v01 = fc[ylo + xh[ix]];
        float v10 = fc[yhi + xl[ix]], v11 = fc[yhi + xh[ix]];
        float top = v00 * (1.f - wxv) + v01 * wxv;
        float bot = v10 * (1.f - wxv) + v11 * wxv;
        float val = top * (1.f - wyv) + bot * wyv;
        m = fmaxf(m, val);
      }
    }
    out[(n * 512 + c) * 49 + r] = m;
  }
}

extern "C" void kernel_launch(void* const* d_in, const int* in_sizes, int n_in,
                              void* d_out, int out_size, void* d_ws, size_t ws_size,
                              hipStream_t stream) {
  const float* net    = (const float*)d_in[0];
  const float* rpn_w  = (const float*)d_in[1];
  const float* rpn_b  = (const float*)d_in[2];
  const float* cls_w  = (const float*)d_in[3];
  const float* cls_b  = (const float*)d_in[4];
  const float* bbox_w = (const float*)d_in[5];
  const float* bbox_b = (const float*)d_in[6];
  float* out = (float*)d_out;

  // d_out (30.1 MB): rpn activations use 18.43 MB; the tail hosts the
  // select scratch (hist/counter/thresh/keys2), all dead before crop_pool.
  float* rpn = out;
  unsigned* hist = (unsigned*)(out + 4608000);            // 262144 u32 (1 MB)
  unsigned* counter = hist + HBUCK;                       // 1 u32
  unsigned long long* thresh = (unsigned long long*)(counter + 2); // 8B-aligned
  unsigned long long* keys2 = thresh + 1;                 // 6000 u64

  float* cls   = (float*)d_ws;                    // 162,000 f
  float* bbox  = cls + 162000;                    // 324,000 f
  float* props = bbox + 324000;                   // 324,000 f
  unsigned long long* keys = (unsigned long long*)(props + 324000);  // 81,000 u64
  float* boxes_k = (float*)(keys + 131072);       // 24,000 f (keep old layout)
  unsigned long long* sup = (unsigned long long*)(boxes_k + PRE * 4); // 6000*94 u64
  float* rois = (float*)(sup + (size_t)PRE * SUPW); // 1,200 f

  dim3 gconv(8, 75, 2);
  conv3_relu<<<gconv, 256, 0, stream>>>(net, rpn_w, rpn_b, rpn);
  conv1x1<<<71, 256, 0, stream>>>(rpn, cls_w, cls_b, bbox_w, bbox_b, cls, bbox);
  decode_score<<<(NANCH + 255) / 256, 256, 0, stream>>>(cls, bbox, props, keys);

  hipMemsetAsync(hist, 0, (size_t)(HBUCK + 1) * 4, stream);
  hist_hi<<<(NANCH + 255) / 256, 256, 0, stream>>>(keys, hist);
  select_thresh<<<1, 1024, 0, stream>>>(keys, hist, thresh);
  compact_ge<<<(NANCH + 255) / 256, 256, 0, stream>>>(keys, thresh, keys2, counter);
  sort8192<<<1, 1024, 65536, stream>>>(keys2);
  gather_topk<<<(PRE + 255) / 256, 256, 0, stream>>>(keys2, props, boxes_k);

  dim3 gsup(SUPW, SUPW);
  nms_sup<<<gsup, 64, 0, stream>>>(boxes_k, sup);
  nms_scan<<<1, 64, 0, stream>>>(sup, boxes_k, rois);
  crop_pool<<<POST, 256, 0, stream>>>(net, rois, out);
}